// Round 5
// baseline (685.349 us; speedup 1.0000x reference)
//
#include <hip/hip_runtime.h>

// NoMCOutModel round 5: producer/consumer wave specialization.
// 1 block (1024 thr = 16 waves) per batch element, 1 per CU (LDS-limited).
// Waves 0-14: per-8-step-window logit GEMM via mfma_f32_16x16x32_f16
//   (B-frags resident in VGPRs, <=20 tiles x 8 f16), exp2, transposed f16
//   store to LDS. Sum pass (576 thr) computes softmax row sums -> s_inv.
// Wave 15: the serial 64x64 matvec recurrence, c[l] in-register, per step
//   8x(ds_read_b128 + 4 fdot2) from the transposed window buffer. No
//   cross-wave traffic inside a window; 2 barriers per 8 steps.
// Round-4 post-mortem: 75% VALUBusy issue-bound on per-thread fdot2 logits;
// MFMA removes that work from the scan-critical path entirely.

namespace {

constexpr int B_ = 256, T_ = 256, M_ = 8, AUX_ = 32, H_ = 64;
constexpr int W_ = 8, NW_ = T_ / W_;          // 8-step windows, 32 of them
constexpr int NCOL = H_ * H_ + M_ * H_;       // 4608 logit columns (Wr || Wj)
constexpr int NTILE = NCOL / 16;              // 288 MFMA col-tiles
constexpr int TPW = 20;                       // max tiles per producer wave (15 waves)
constexpr float LOG2E = 1.4426950408889634f;

typedef __fp16 f16x2 __attribute__((ext_vector_type(2)));
typedef __fp16 f16x8 __attribute__((ext_vector_type(8)));
typedef float  f32x4 __attribute__((ext_vector_type(4)));

union V8 { f16x8 v; f16x2 p[4]; };

#if __has_builtin(__builtin_amdgcn_exp2f)
#define EXP2(x) __builtin_amdgcn_exp2f(x)
#else
#define EXP2(x) exp2f(x)
#endif

__device__ __forceinline__ float dot2(f16x2 a, f16x2 b, float c) {
    return __builtin_amdgcn_fdot2(a, b, c, false);
}

template <int CTRL>
__device__ __forceinline__ float dpp_add(float v) {
    int t = __builtin_amdgcn_update_dpp(0, __builtin_bit_cast(int, v),
                                        CTRL, 0xf, 0xf, true);
    return v + __builtin_bit_cast(float, t);
}
__device__ __forceinline__ float sum64_uni(float v) {
    v = dpp_add<0x111>(v); v = dpp_add<0x112>(v); v = dpp_add<0x114>(v);
    v = dpp_add<0x118>(v); v = dpp_add<0x142>(v); v = dpp_add<0x143>(v);
    return __builtin_bit_cast(float,
        __builtin_amdgcn_readlane(__builtin_bit_cast(int, v), 63));
}

// Per-parity window buffer: 75904 B.  RT[t][h>>3][k][h&7] = exp(logit) f16;
// scan lane l reads RT[t][hb][l][0..7] as one b128 (16B-contig per lane).
struct __align__(16) Buf {
    __fp16 RT[W_][8][64][8];   // 65536 B
    __fp16 JT[W_][64][8];      //  8192 B  JT[t][h_dest][m]
    float  sinv[W_][64];       //  2048 B  1/rowsum for R
    __fp16 xj[W_][8];          //   128 B  x_m[t][m]/rowsum_J  (16B rows)
};

__global__ __launch_bounds__(1024, 4)
void nomc_fused(const float* __restrict__ x_m, const float* __restrict__ x_a,
                const float* __restrict__ Wj, const float* __restrict__ bj,
                const float* __restrict__ Wr, const float* __restrict__ br,
                const float* __restrict__ Wo, const float* __restrict__ bo,
                const float* __restrict__ Wfc, const float* __restrict__ bfc,
                float* __restrict__ out)
{
    const int b   = blockIdx.x;
    const int tid = threadIdx.x;
    const int w   = tid >> 6;
    const int l   = tid & 63;
    const int l15 = l & 15;
    const int q   = l >> 4;

    __shared__ Buf buf[2];                       // 151808 B
    __shared__ __fp16 bias_l[NCOL];              //   9216 B (log2e-scaled)
    __shared__ __align__(16) __fp16 cbuf[64];    //    128 B (scan-wave local)
    // total 161152 <= 163840

    // ---- stage bias ----
    for (int i = tid; i < NCOL; i += 1024) {
        float v = (i < H_ * H_) ? br[i] : bj[i - H_ * H_];
        bias_l[i] = (__fp16)(v * LOG2E);
    }

    // ---- preload resident B-fragments (producer waves 0..14) ----
    // wave w owns tiles [w*20, min(w*20+20, 288)); B[k][n]: n=lane&15, k=q*8+j
    f16x8 bf[TPW];
    const int mine = (w < 15) ? ((288 - w * TPW) < TPW ? (288 - w * TPW) : TPW) : 0;
#pragma unroll
    for (int c = 0; c < TPW; ++c) {
        if (c < mine) {
            const int n = (w * TPW + c) * 16 + l15;
            const float* src; int stride;
            if (n < H_ * H_) { src = Wr + n;            stride = H_ * H_; }
            else             { src = Wj + (n - H_ * H_); stride = M_ * H_; }
            f16x8 v;
#pragma unroll
            for (int j = 0; j < 8; ++j)
                v[j] = (__fp16)(src[(size_t)(q * 8 + j) * stride] * LOG2E);
            bf[c] = v;
        }
    }

    // ---- producer: window win -> raw exp(logits) into Bf (transposed) ----
    auto produce = [&](int win, Buf& Bf) {
        const int t = win * W_ + (l15 & 7);          // rows 8-15 duplicate 0-7
        const float* xa = x_a + ((size_t)b * T_ + t) * AUX_ + q * 8;
        f16x8 af;
#pragma unroll
        for (int j = 0; j < 8; ++j) af[j] = (__fp16)xa[j];
#pragma unroll
        for (int c = 0; c < TPW; ++c) {
            if (c < mine) {
                f32x4 acc = {0.f, 0.f, 0.f, 0.f};
                acc = __builtin_amdgcn_mfma_f32_16x16x32_f16(af, bf[c], acc, 0, 0, 0);
                const int n = (w * TPW + c) * 16 + l15;
                const float bcol = (float)bias_l[n];
                if (q < 2) {                          // rows 0-7 valid only
#pragma unroll
                    for (int r = 0; r < 4; ++r) {
                        const int tl = q * 4 + r;     // local t
                        const __fp16 eh = (__fp16)EXP2(acc[r] + bcol);
                        if (n < H_ * H_) {
                            const int h = n >> 6, k = n & 63;
                            Bf.RT[tl][h >> 3][k][h & 7] = eh;
                        } else {
                            const int n2 = n - H_ * H_;
                            Bf.JT[tl][n2 & 63][n2 >> 6] = eh;
                        }
                    }
                }
            }
        }
    };

    // ---- sum pass: softmax row sums -> sinv / xj (576 threads) ----
    auto sumpass = [&](int win, Buf& Bf) {
        if (tid < W_ * H_) {                          // 512 R rows (t,h)
            const int t = tid >> 6, h = tid & 63;
            const int hb = h >> 3, hc = h & 7;
            float s = 0.f;
#pragma unroll 8
            for (int kk = 0; kk < 64; ++kk) {
                const int k = (kk + tid) & 63;        // rotate: avoid bank pileup
                s += (float)Bf.RT[t][hb][k][hc];
            }
            Bf.sinv[t][h] = __builtin_amdgcn_rcpf(s);
        } else if (tid < W_ * H_ + W_ * M_) {         // 64 J rows (t,m)
            const int jd = tid - W_ * H_;
            const int t = jd >> 3, m = jd & 7;
            float s = 0.f;
#pragma unroll 8
            for (int kk = 0; kk < 64; ++kk) {
                const int k = (kk + jd) & 63;
                s += (float)Bf.JT[t][k][m];
            }
            const float xm = x_m[((size_t)b * T_ + win * W_ + t) * M_ + m];
            Bf.xj[t][m] = (__fp16)(xm * __builtin_amdgcn_rcpf(s));
        }
    };

    // ---- scan: 8 steps from Bf; c[l] in-register (wave 15 only) ----
    float c = 0.f;
    auto scan8 = [&](Buf& Bf) {
#pragma unroll
        for (int u = 0; u < W_; ++u) {
            cbuf[l] = (__fp16)(c * Bf.sinv[u][l]);    // chat = c/s, f16
            float a0 = 0.f, a1 = 0.f, a2 = 0.f, a3 = 0.f;
#pragma unroll
            for (int hb = 0; hb < 8; ++hb) {
                V8 ev, cv;
                ev.v = *(const f16x8*)&Bf.RT[u][hb][l][0];   // b128, lane-contig
                cv.v = *(const f16x8*)&cbuf[hb * 8];         // b128 broadcast
                a0 = dot2(ev.p[0], cv.p[0], a0);
                a1 = dot2(ev.p[1], cv.p[1], a1);
                a2 = dot2(ev.p[2], cv.p[2], a2);
                a3 = dot2(ev.p[3], cv.p[3], a3);
            }
            V8 jv, xv;                                        // junction inflow
            jv.v = *(const f16x8*)&Bf.JT[u][l][0];
            xv.v = *(const f16x8*)&Bf.xj[u][0];
            a0 = dot2(jv.p[0], xv.p[0], a0);
            a1 = dot2(jv.p[1], xv.p[1], a1);
            a2 = dot2(jv.p[2], xv.p[2], a2);
            a3 = dot2(jv.p[3], xv.p[3], a3);
            c = (a0 + a1) + (a2 + a3);
        }
    };

    const bool is_scan = (w == 15);

    // ---- prologue: window 0 ----
    if (!is_scan) produce(0, buf[0]);
    __syncthreads();
    sumpass(0, buf[0]);
    __syncthreads();

    // ---- main loop: scan window u while producing u+1 ----
    for (int u = 0; u < NW_; ++u) {
        const int p = u & 1;
        if (is_scan)            scan8(buf[p]);
        else if (u + 1 < NW_)   produce(u + 1, buf[p ^ 1]);
        __syncthreads();
        if (u + 1 < NW_) sumpass(u + 1, buf[p ^ 1]);
        __syncthreads();
    }

    // ---- epilogue (scan wave): out = (sigmoid(xa_T@Wo+bo)*c_T)@Wfc + bfc ----
    if (is_scan) {
        const float* xa = x_a + ((size_t)b * T_ + (T_ - 1)) * AUX_;
        float L = bo[l];
#pragma unroll
        for (int a = 0; a < AUX_; ++a) L = fmaf(xa[a], Wo[a * H_ + l], L);
        const float o = 1.0f / (1.0f + __expf(-L));
        float p = (o * c) * Wfc[l];
        p = sum64_uni(p);
        if (l == 0) out[b] = p + bfc[0];
        out[B_ + b * H_ + l] = c;                     // c_final, coalesced
    }
}

} // namespace

extern "C" void kernel_launch(void* const* d_in, const int* in_sizes, int n_in,
                              void* d_out, int out_size, void* d_ws, size_t ws_size,
                              hipStream_t stream) {
    const float* x_m = (const float*)d_in[0];
    const float* x_a = (const float*)d_in[1];
    const float* Wj  = (const float*)d_in[2];
    const float* bj  = (const float*)d_in[3];
    const float* Wr  = (const float*)d_in[4];
    const float* br  = (const float*)d_in[5];
    const float* Wo  = (const float*)d_in[6];
    const float* bo  = (const float*)d_in[7];
    const float* Wfc = (const float*)d_in[8];
    const float* bfc = (const float*)d_in[9];
    float* out = (float*)d_out;

    hipLaunchKernelGGL(nomc_fused, dim3(B_), dim3(1024), 0, stream,
                       x_m, x_a, Wj, bj, Wr, br, Wo, bo, Wfc, bfc, out);
}

// Round 6
// 318.479 us; speedup vs baseline: 2.1519x; 2.1519x over previous
//
#include <hip/hip_runtime.h>

// NoMCOutModel round 6: streamed-MFMA producer + single-wave scan, serialized
// 16-step windows, one block (16 waves) per batch element / CU.
//
// Round-5 post-mortem: resident B-frags (80 VGPR) spilled under the observed
// 64-VGPR cap -> 509 MB scratch FETCH; 16B-stride f16 stores -> 5.7e7 LDS
// bank conflicts. This round: (1) weights pre-converted to f16 B-frag layout
// in d_ws by a prep kernel, streamed from L2 per use (no residency, ~50 VGPR
// peak); (2) all 16 MFMA rows used = 16 timesteps/pass (round 5 wasted half);
// (3) softmax row sums via DPP sum16 inside the producer (whole groups-of-4
// tiles per wave = complete rows); (4) XOR-swizzled store position
// p = (h&7)^4*bit3(k) -> conflict-free stores; scan un-swizzles via two b64
// broadcast reads of c-hat.

namespace {

constexpr int B_ = 256, T_ = 256, M_ = 8, AUX_ = 32, H_ = 64;
constexpr int NTILE = 288;               // (64*64 + 8*64)/16 logit col-tiles
constexpr float LOG2E = 1.4426950408889634f;

typedef __fp16 f16x2 __attribute__((ext_vector_type(2)));
typedef __fp16 f16x4 __attribute__((ext_vector_type(4)));
typedef __fp16 f16x8 __attribute__((ext_vector_type(8)));
typedef float  f32x4 __attribute__((ext_vector_type(4)));
typedef int    i32x4 __attribute__((ext_vector_type(4)));

union V8 { f16x8 v; f16x2 p[4]; i32x4 i; };
struct __align__(8) V4 { f16x2 p[2]; };

#if __has_builtin(__builtin_amdgcn_exp2f)
#define EXP2(x) __builtin_amdgcn_exp2f(x)
#else
#define EXP2(x) exp2f(x)
#endif

__device__ __forceinline__ float dot2(f16x2 a, f16x2 b, float c) {
    return __builtin_amdgcn_fdot2(a, b, c, false);
}

template <int CTRL>
__device__ __forceinline__ float dpp_add(float v) {
    int t = __builtin_amdgcn_update_dpp(0, __builtin_bit_cast(int, v),
                                        CTRL, 0xf, 0xf, true);
    return v + __builtin_bit_cast(float, t);
}
// sum within each 16-lane group, result in all lanes of the group
__device__ __forceinline__ float sum16_all(float v) {
    v = dpp_add<0xB1>(v);   // quad_perm [1,0,3,2]
    v = dpp_add<0x4E>(v);   // quad_perm [2,3,0,1]
    v = dpp_add<0x141>(v);  // row_half_mirror
    v = dpp_add<0x140>(v);  // row_mirror
    return v;
}
__device__ __forceinline__ float sum64_uni(float v) {
    v = dpp_add<0x111>(v); v = dpp_add<0x112>(v); v = dpp_add<0x114>(v);
    v = dpp_add<0x118>(v); v = dpp_add<0x142>(v); v = dpp_add<0x143>(v);
    return __builtin_bit_cast(float,
        __builtin_amdgcn_readlane(__builtin_bit_cast(int, v), 63));
}

// ---------------- prep: W -> f16 MFMA B-frag layout in ws ----------------
// ws[gt*1024 + lane*16] : f16x8 frag, B[k = (lane>>4)*8 + j][n = gt*16+(lane&15)]
// ws + 288*1024 : float bias[4608] (log2e-scaled)
__global__ __launch_bounds__(64)
void nomc_prep(const float* __restrict__ Wj, const float* __restrict__ bj,
               const float* __restrict__ Wr, const float* __restrict__ br,
               void* __restrict__ ws)
{
    const int gt = blockIdx.x;           // 0..287
    const int l = threadIdx.x, q = l >> 4, l15 = l & 15;
    const float* src; const float* bsrc; int stride;
    if (gt < 256) { const int n = gt * 16 + l15;        src = Wr + n; bsrc = br + n; stride = 4096; }
    else          { const int n = (gt - 256) * 16 + l15; src = Wj + n; bsrc = bj + n; stride = 512; }
    V8 v;
#pragma unroll
    for (int j = 0; j < 4; ++j) {
        const float f0 = src[(q * 8 + 2 * j)     * stride] * LOG2E;
        const float f1 = src[(q * 8 + 2 * j + 1) * stride] * LOG2E;
        v.p[j] = __builtin_amdgcn_cvt_pkrtz(f0, f1);
    }
    *(i32x4*)((char*)ws + (size_t)gt * 1024 + l * 16) = v.i;
    if (l < 16)
        ((float*)((char*)ws + NTILE * 1024))[gt * 16 + l] = bsrc[0] * LOG2E;
}

// ---------------- main ----------------
__global__ __launch_bounds__(1024, 4)
void nomc_main(const float* __restrict__ x_m, const float* __restrict__ x_a,
               const float* __restrict__ Wo, const float* __restrict__ bo,
               const float* __restrict__ Wfc, const float* __restrict__ bfc,
               const void* __restrict__ ws, float* __restrict__ out)
{
    const int b = blockIdx.x, tid = threadIdx.x;
    const int w = tid >> 6, l = tid & 63, q = l >> 4, l15 = l & 15;

    // RT[t][h>>3][k][p], p = (h&7) ^ 4*bit3(k): swizzled exp(logits), f16
    __shared__ __align__(16) __fp16 RT[16][8][64][8];   // 131072 B
    __shared__ __align__(16) __fp16 JT[16][64][8];      //  16384 B  [t][h_dest][m-swz]
    __shared__ float sinv[16][64];                      //   4096 B
    __shared__ __align__(16) __fp16 xj[16][8];          //    256 B  xm/s_j
    __shared__ float xm_lds[T_][M_];                    //   8192 B
    __shared__ __align__(16) __fp16 cbuf[64];           //    128 B
    // total 160128 <= 163840

    {   // stage x_m once
        const float* xmb = x_m + (size_t)b * T_ * M_;
        for (int i = tid; i < T_ * M_; i += 1024) (&xm_lds[0][0])[i] = xmb[i];
    }
    __syncthreads();

    // wave w owns groups [g0, g0+ngrp); each group = 4 tiles = one full row set
    const int ngrp = (w < 8) ? 5 : 4;
    const int g0   = (w < 8) ? w * 5 : 40 + (w - 8) * 4;
    const char* wsb = (const char*)ws;
    const float* wbias = (const float*)(wsb + NTILE * 1024);

    float c = 0.f;

    for (int it = 0; it < 16; ++it) {
        // ================= produce: 16 timesteps of exp(logits) =================
        V8 af;
        {   // A-frag: row m = l15 -> t = it*16+l15; k = q*8+j
            const float* xa = x_a + ((size_t)b * T_ + it * 16 + l15) * AUX_ + q * 8;
            const f32x4 x0 = *(const f32x4*)xa;
            const f32x4 x1 = *(const f32x4*)(xa + 4);
            af.p[0] = __builtin_amdgcn_cvt_pkrtz(x0.x, x0.y);
            af.p[1] = __builtin_amdgcn_cvt_pkrtz(x0.z, x0.w);
            af.p[2] = __builtin_amdgcn_cvt_pkrtz(x1.x, x1.y);
            af.p[3] = __builtin_amdgcn_cvt_pkrtz(x1.z, x1.w);
        }
        const int sw = ((l15 >> 3) & 1) << 2;            // 4*bit3(k)

        for (int g = 0; g < ngrp; ++g) {
            const int gg = g0 + g;                       // 0..63 = R row h; 64..71 = J row m
            float sr0 = 0.f, sr1 = 0.f, sr2 = 0.f, sr3 = 0.f;
#pragma unroll
            for (int tt = 0; tt < 4; ++tt) {
                const int gt = gg * 4 + tt;
                V8 bf; bf.i = *(const i32x4*)(wsb + (size_t)gt * 1024 + l * 16);
                const float bv = wbias[gt * 16 + l15];
                f32x4 acc = {bv, bv, bv, bv};
                acc = __builtin_amdgcn_mfma_f32_16x16x32_f16(af.v, bf.v, acc, 0, 0, 0);
                const float e0 = EXP2(acc[0]), e1 = EXP2(acc[1]);
                const float e2 = EXP2(acc[2]), e3 = EXP2(acc[3]);
                const int kk = (tt << 4) + l15;          // col within row: gt&3 == tt
                if (gg < 64) {
                    const int hb = gg >> 3, p = (gg & 7) ^ sw;
                    RT[q * 4 + 0][hb][kk][p] = (__fp16)e0;
                    RT[q * 4 + 1][hb][kk][p] = (__fp16)e1;
                    RT[q * 4 + 2][hb][kk][p] = (__fp16)e2;
                    RT[q * 4 + 3][hb][kk][p] = (__fp16)e3;
                } else {
                    const int p = (gg - 64) ^ sw;
                    JT[q * 4 + 0][kk][p] = (__fp16)e0;
                    JT[q * 4 + 1][kk][p] = (__fp16)e1;
                    JT[q * 4 + 2][kk][p] = (__fp16)e2;
                    JT[q * 4 + 3][kk][p] = (__fp16)e3;
                }
                sr0 += sum16_all(e0); sr1 += sum16_all(e1);
                sr2 += sum16_all(e2); sr3 += sum16_all(e3);
            }
            if (l15 == 0) {
                if (gg < 64) {
                    sinv[q * 4 + 0][gg] = __builtin_amdgcn_rcpf(sr0);
                    sinv[q * 4 + 1][gg] = __builtin_amdgcn_rcpf(sr1);
                    sinv[q * 4 + 2][gg] = __builtin_amdgcn_rcpf(sr2);
                    sinv[q * 4 + 3][gg] = __builtin_amdgcn_rcpf(sr3);
                } else {
                    const int m = gg - 64;
                    xj[q * 4 + 0][m] = (__fp16)(xm_lds[it * 16 + q * 4 + 0][m] * __builtin_amdgcn_rcpf(sr0));
                    xj[q * 4 + 1][m] = (__fp16)(xm_lds[it * 16 + q * 4 + 1][m] * __builtin_amdgcn_rcpf(sr1));
                    xj[q * 4 + 2][m] = (__fp16)(xm_lds[it * 16 + q * 4 + 2][m] * __builtin_amdgcn_rcpf(sr2));
                    xj[q * 4 + 3][m] = (__fp16)(xm_lds[it * 16 + q * 4 + 3][m] * __builtin_amdgcn_rcpf(sr3));
                }
            }
        }
        __syncthreads();

        // ================= scan: 16 serial steps (wave 15 only) =================
        if (w == 15) {
            const int s8 = ((l >> 3) & 1) << 3;          // byte offset 8*bit3(l)
#pragma unroll 2
            for (int u = 0; u < 16; ++u) {
                cbuf[l] = (__fp16)(c * sinv[u][l]);      // wave-local LDS round trip
                float a0 = 0.f, a1 = 0.f, a2 = 0.f, a3 = 0.f;
#pragma unroll
                for (int hb = 0; hb < 8; ++hb) {
                    V8 ev; ev.v = *(const f16x8*)&RT[u][hb][l][0];   // contiguous b128
                    const V4 lo = *(const V4*)((const char*)&cbuf[hb * 8] + s8);
                    const V4 hi = *(const V4*)((const char*)&cbuf[hb * 8] + (8 - s8));
                    a0 = dot2(ev.p[0], lo.p[0], a0);
                    a1 = dot2(ev.p[1], lo.p[1], a1);
                    a2 = dot2(ev.p[2], hi.p[0], a2);
                    a3 = dot2(ev.p[3], hi.p[1], a3);
                }
                V8 jv; jv.v = *(const f16x8*)&JT[u][l][0];
                const V4 xlo = *(const V4*)((const char*)&xj[u][0] + s8);
                const V4 xhi = *(const V4*)((const char*)&xj[u][0] + (8 - s8));
                a0 = dot2(jv.p[0], xlo.p[0], a0);
                a1 = dot2(jv.p[1], xlo.p[1], a1);
                a2 = dot2(jv.p[2], xhi.p[0], a2);
                a3 = dot2(jv.p[3], xhi.p[1], a3);
                c = (a0 + a1) + (a2 + a3);
            }
        }
        __syncthreads();
    }

    // ---- epilogue: out = (sigmoid(xa_T@Wo+bo) * c_T) @ Wfc + bfc ----
    if (w == 15) {
        const float* xa = x_a + ((size_t)b * T_ + (T_ - 1)) * AUX_;
        float L = bo[l];
#pragma unroll
        for (int a = 0; a < AUX_; ++a) L = fmaf(xa[a], Wo[a * H_ + l], L);
        const float o = 1.0f / (1.0f + __expf(-L));
        float p = (o * c) * Wfc[l];
        p = sum64_uni(p);
        if (l == 0) out[b] = p + bfc[0];
        out[B_ + b * H_ + l] = c;                        // c_final, coalesced
    }
}

} // namespace

extern "C" void kernel_launch(void* const* d_in, const int* in_sizes, int n_in,
                              void* d_out, int out_size, void* d_ws, size_t ws_size,
                              hipStream_t stream) {
    const float* x_m = (const float*)d_in[0];
    const float* x_a = (const float*)d_in[1];
    const float* Wj  = (const float*)d_in[2];
    const float* bj  = (const float*)d_in[3];
    const float* Wr  = (const float*)d_in[4];
    const float* br  = (const float*)d_in[5];
    const float* Wo  = (const float*)d_in[6];
    const float* bo  = (const float*)d_in[7];
    const float* Wfc = (const float*)d_in[8];
    const float* bfc = (const float*)d_in[9];
    float* out = (float*)d_out;

    hipLaunchKernelGGL(nomc_prep, dim3(NTILE), dim3(64), 0, stream,
                       Wj, bj, Wr, br, d_ws);
    hipLaunchKernelGGL(nomc_main, dim3(B_), dim3(1024), 0, stream,
                       x_m, x_a, Wo, bo, Wfc, bfc, d_ws, out);
}

// Round 7
// 288.706 us; speedup vs baseline: 2.3739x; 1.1031x over previous
//
#include <hip/hip_runtime.h>

// NoMCOutModel round 7: round-6 structure (streamed-MFMA producer + 1-wave
// scan, serialized 16-step windows) with two issue/latency trims:
//  (a) produce row-sums: accumulate esum over the 4 tt tiles with plain adds,
//      ONE sum16_all (4 DPP) per r instead of four (was ~half of produce issue);
//  (b) scan: all 9 RT/JT b128 loads issued BEFORE the c-hat ds_write (no data
//      dep), hiding load latency under the store->load wait; 8 accumulators
//      cut the dot chain depth 11 -> 5.
// Round-6 counters: FETCH 6.4 MB (no spill, VGPR 52), VALUBusy 49.6%,
// MfmaUtil 3%, conflicts 1.2e7 (~19us/CU, tolerated). Keep VGPR need < 64
// (observed allocator cap with MFMA present; round-5 spilled above it).

namespace {

constexpr int B_ = 256, T_ = 256, M_ = 8, AUX_ = 32, H_ = 64;
constexpr int NTILE = 288;               // (64*64 + 8*64)/16 logit col-tiles
constexpr float LOG2E = 1.4426950408889634f;

typedef __fp16 f16x2 __attribute__((ext_vector_type(2)));
typedef __fp16 f16x8 __attribute__((ext_vector_type(8)));
typedef float  f32x4 __attribute__((ext_vector_type(4)));
typedef int    i32x4 __attribute__((ext_vector_type(4)));

union V8 { f16x8 v; f16x2 p[4]; i32x4 i; };
struct __align__(8) V4 { f16x2 p[2]; };

#if __has_builtin(__builtin_amdgcn_exp2f)
#define EXP2(x) __builtin_amdgcn_exp2f(x)
#else
#define EXP2(x) exp2f(x)
#endif

__device__ __forceinline__ float dot2(f16x2 a, f16x2 b, float c) {
    return __builtin_amdgcn_fdot2(a, b, c, false);
}

template <int CTRL>
__device__ __forceinline__ float dpp_add(float v) {
    int t = __builtin_amdgcn_update_dpp(0, __builtin_bit_cast(int, v),
                                        CTRL, 0xf, 0xf, true);
    return v + __builtin_bit_cast(float, t);
}
// sum within each 16-lane group, result in all lanes of the group
__device__ __forceinline__ float sum16_all(float v) {
    v = dpp_add<0xB1>(v);   // quad_perm [1,0,3,2]
    v = dpp_add<0x4E>(v);   // quad_perm [2,3,0,1]
    v = dpp_add<0x141>(v);  // row_half_mirror
    v = dpp_add<0x140>(v);  // row_mirror
    return v;
}
__device__ __forceinline__ float sum64_uni(float v) {
    v = dpp_add<0x111>(v); v = dpp_add<0x112>(v); v = dpp_add<0x114>(v);
    v = dpp_add<0x118>(v); v = dpp_add<0x142>(v); v = dpp_add<0x143>(v);
    return __builtin_bit_cast(float,
        __builtin_amdgcn_readlane(__builtin_bit_cast(int, v), 63));
}

// ---------------- prep: W -> f16 MFMA B-frag layout in ws ----------------
// ws[gt*1024 + lane*16] : f16x8 frag, B[k = (lane>>4)*8 + j][n = gt*16+(lane&15)]
// ws + 288*1024 : float bias[4608] (log2e-scaled)
__global__ __launch_bounds__(64)
void nomc_prep(const float* __restrict__ Wj, const float* __restrict__ bj,
               const float* __restrict__ Wr, const float* __restrict__ br,
               void* __restrict__ ws)
{
    const int gt = blockIdx.x;           // 0..287
    const int l = threadIdx.x, q = l >> 4, l15 = l & 15;
    const float* src; const float* bsrc; int stride;
    if (gt < 256) { const int n = gt * 16 + l15;        src = Wr + n; bsrc = br + n; stride = 4096; }
    else          { const int n = (gt - 256) * 16 + l15; src = Wj + n; bsrc = bj + n; stride = 512; }
    V8 v;
#pragma unroll
    for (int j = 0; j < 4; ++j) {
        const float f0 = src[(q * 8 + 2 * j)     * stride] * LOG2E;
        const float f1 = src[(q * 8 + 2 * j + 1) * stride] * LOG2E;
        v.p[j] = __builtin_amdgcn_cvt_pkrtz(f0, f1);
    }
    *(i32x4*)((char*)ws + (size_t)gt * 1024 + l * 16) = v.i;
    if (l < 16)
        ((float*)((char*)ws + NTILE * 1024))[gt * 16 + l] = bsrc[0] * LOG2E;
}

// ---------------- main ----------------
__global__ __launch_bounds__(1024, 4)
void nomc_main(const float* __restrict__ x_m, const float* __restrict__ x_a,
               const float* __restrict__ Wo, const float* __restrict__ bo,
               const float* __restrict__ Wfc, const float* __restrict__ bfc,
               const void* __restrict__ ws, float* __restrict__ out)
{
    const int b = blockIdx.x, tid = threadIdx.x;
    const int w = tid >> 6, l = tid & 63, q = l >> 4, l15 = l & 15;

    // RT[t][h>>3][k][p], p = (h&7) ^ 4*bit3(k): swizzled exp(logits), f16
    __shared__ __align__(16) __fp16 RT[16][8][64][8];   // 131072 B
    __shared__ __align__(16) __fp16 JT[16][64][8];      //  16384 B  [t][h_dest][m-swz]
    __shared__ float sinv[16][64];                      //   4096 B
    __shared__ __align__(16) __fp16 xj[16][8];          //    256 B  xm/s_j
    __shared__ float xm_lds[T_][M_];                    //   8192 B
    __shared__ __align__(16) __fp16 cbuf[64];           //    128 B
    // total 160128 <= 163840

    {   // stage x_m once
        const float* xmb = x_m + (size_t)b * T_ * M_;
        for (int i = tid; i < T_ * M_; i += 1024) (&xm_lds[0][0])[i] = xmb[i];
    }
    __syncthreads();

    // wave w owns groups [g0, g0+ngrp); each group = 4 tiles = one full row set
    const int ngrp = (w < 8) ? 5 : 4;
    const int g0   = (w < 8) ? w * 5 : 40 + (w - 8) * 4;
    const char* wsb = (const char*)ws;
    const float* wbias = (const float*)(wsb + NTILE * 1024);

    float c = 0.f;

    for (int it = 0; it < 16; ++it) {
        // ================= produce: 16 timesteps of exp(logits) =================
        V8 af;
        {   // A-frag: row m = l15 -> t = it*16+l15; k = q*8+j
            const float* xa = x_a + ((size_t)b * T_ + it * 16 + l15) * AUX_ + q * 8;
            const f32x4 x0 = *(const f32x4*)xa;
            const f32x4 x1 = *(const f32x4*)(xa + 4);
            af.p[0] = __builtin_amdgcn_cvt_pkrtz(x0.x, x0.y);
            af.p[1] = __builtin_amdgcn_cvt_pkrtz(x0.z, x0.w);
            af.p[2] = __builtin_amdgcn_cvt_pkrtz(x1.x, x1.y);
            af.p[3] = __builtin_amdgcn_cvt_pkrtz(x1.z, x1.w);
        }
        const int sw = ((l15 >> 3) & 1) << 2;            // 4*bit3(k)

        for (int g = 0; g < ngrp; ++g) {
            const int gg = g0 + g;                       // 0..63 = R row h; 64..71 = J row m
            float es0 = 0.f, es1 = 0.f, es2 = 0.f, es3 = 0.f;
#pragma unroll
            for (int tt = 0; tt < 4; ++tt) {
                const int gt = gg * 4 + tt;
                V8 bf; bf.i = *(const i32x4*)(wsb + (size_t)gt * 1024 + l * 16);
                const float bv = wbias[gt * 16 + l15];
                f32x4 acc = {bv, bv, bv, bv};
                acc = __builtin_amdgcn_mfma_f32_16x16x32_f16(af.v, bf.v, acc, 0, 0, 0);
                const float e0 = EXP2(acc[0]), e1 = EXP2(acc[1]);
                const float e2 = EXP2(acc[2]), e3 = EXP2(acc[3]);
                const int kk = (tt << 4) + l15;          // col within row: gt&3 == tt
                if (gg < 64) {
                    const int hb = gg >> 3, p = (gg & 7) ^ sw;
                    RT[q * 4 + 0][hb][kk][p] = (__fp16)e0;
                    RT[q * 4 + 1][hb][kk][p] = (__fp16)e1;
                    RT[q * 4 + 2][hb][kk][p] = (__fp16)e2;
                    RT[q * 4 + 3][hb][kk][p] = (__fp16)e3;
                } else {
                    const int p = (gg - 64) ^ sw;
                    JT[q * 4 + 0][kk][p] = (__fp16)e0;
                    JT[q * 4 + 1][kk][p] = (__fp16)e1;
                    JT[q * 4 + 2][kk][p] = (__fp16)e2;
                    JT[q * 4 + 3][kk][p] = (__fp16)e3;
                }
                es0 += e0; es1 += e1; es2 += e2; es3 += e3;
            }
            // ONE cross-lane reduce per r (was 4): sum over k = sum_tt sum_lanes
            const float sr0 = sum16_all(es0), sr1 = sum16_all(es1);
            const float sr2 = sum16_all(es2), sr3 = sum16_all(es3);
            if (l15 == 0) {
                if (gg < 64) {
                    sinv[q * 4 + 0][gg] = __builtin_amdgcn_rcpf(sr0);
                    sinv[q * 4 + 1][gg] = __builtin_amdgcn_rcpf(sr1);
                    sinv[q * 4 + 2][gg] = __builtin_amdgcn_rcpf(sr2);
                    sinv[q * 4 + 3][gg] = __builtin_amdgcn_rcpf(sr3);
                } else {
                    const int m = gg - 64;
                    xj[q * 4 + 0][m] = (__fp16)(xm_lds[it * 16 + q * 4 + 0][m] * __builtin_amdgcn_rcpf(sr0));
                    xj[q * 4 + 1][m] = (__fp16)(xm_lds[it * 16 + q * 4 + 1][m] * __builtin_amdgcn_rcpf(sr1));
                    xj[q * 4 + 2][m] = (__fp16)(xm_lds[it * 16 + q * 4 + 2][m] * __builtin_amdgcn_rcpf(sr2));
                    xj[q * 4 + 3][m] = (__fp16)(xm_lds[it * 16 + q * 4 + 3][m] * __builtin_amdgcn_rcpf(sr3));
                }
            }
        }
        __syncthreads();

        // ================= scan: 16 serial steps (wave 15 only) =================
        if (w == 15) {
            const int s8 = ((l >> 3) & 1) << 3;          // byte offset 8*bit3(l)
#pragma unroll 4
            for (int u = 0; u < 16; ++u) {
                // issue ALL e-matrix loads first -- they do not depend on c-hat,
                // so they overlap the cbuf store->load round trip below.
                V8 ev[8], jv;
#pragma unroll
                for (int hb = 0; hb < 8; ++hb)
                    ev[hb].v = *(const f16x8*)&RT[u][hb][l][0];   // contiguous b128
                jv.v = *(const f16x8*)&JT[u][l][0];
                cbuf[l] = (__fp16)(c * sinv[u][l]);               // wave-local round trip
                float a0 = 0.f, a1 = 0.f, a2 = 0.f, a3 = 0.f;
                float a4 = 0.f, a5 = 0.f, a6 = 0.f, a7 = 0.f;
#pragma unroll
                for (int hb = 0; hb < 8; ++hb) {
                    const V4 lo = *(const V4*)((const char*)&cbuf[hb * 8] + s8);
                    const V4 hi = *(const V4*)((const char*)&cbuf[hb * 8] + (8 - s8));
                    const int r = hb >> 1;               // spread over 8 accumulators
                    if (hb & 1) {
                        a4 = dot2(ev[hb].p[0], lo.p[0], a4);
                        a5 = dot2(ev[hb].p[1], lo.p[1], a5);
                        a6 = dot2(ev[hb].p[2], hi.p[0], a6);
                        a7 = dot2(ev[hb].p[3], hi.p[1], a7);
                    } else {
                        a0 = dot2(ev[hb].p[0], lo.p[0], a0);
                        a1 = dot2(ev[hb].p[1], lo.p[1], a1);
                        a2 = dot2(ev[hb].p[2], hi.p[0], a2);
                        a3 = dot2(ev[hb].p[3], hi.p[1], a3);
                    }
                    (void)r;
                }
                const V4 xlo = *(const V4*)((const char*)&xj[u][0] + s8);
                const V4 xhi = *(const V4*)((const char*)&xj[u][0] + (8 - s8));
                a0 = dot2(jv.p[0], xlo.p[0], a0);
                a1 = dot2(jv.p[1], xlo.p[1], a1);
                a2 = dot2(jv.p[2], xhi.p[0], a2);
                a3 = dot2(jv.p[3], xhi.p[1], a3);
                c = ((a0 + a4) + (a1 + a5)) + ((a2 + a6) + (a3 + a7));
            }
        }
        __syncthreads();
    }

    // ---- epilogue: out = (sigmoid(xa_T@Wo+bo) * c_T) @ Wfc + bfc ----
    if (w == 15) {
        const float* xa = x_a + ((size_t)b * T_ + (T_ - 1)) * AUX_;
        float L = bo[l];
#pragma unroll
        for (int a = 0; a < AUX_; ++a) L = fmaf(xa[a], Wo[a * H_ + l], L);
        const float o = 1.0f / (1.0f + __expf(-L));
        float p = (o * c) * Wfc[l];
        p = sum64_uni(p);
        if (l == 0) out[b] = p + bfc[0];
        out[B_ + b * H_ + l] = c;                        // c_final, coalesced
    }
}

} // namespace

extern "C" void kernel_launch(void* const* d_in, const int* in_sizes, int n_in,
                              void* d_out, int out_size, void* d_ws, size_t ws_size,
                              hipStream_t stream) {
    const float* x_m = (const float*)d_in[0];
    const float* x_a = (const float*)d_in[1];
    const float* Wj  = (const float*)d_in[2];
    const float* bj  = (const float*)d_in[3];
    const float* Wr  = (const float*)d_in[4];
    const float* br  = (const float*)d_in[5];
    const float* Wo  = (const float*)d_in[6];
    const float* bo  = (const float*)d_in[7];
    const float* Wfc = (const float*)d_in[8];
    const float* bfc = (const float*)d_in[9];
    float* out = (float*)d_out;

    hipLaunchKernelGGL(nomc_prep, dim3(NTILE), dim3(64), 0, stream,
                       Wj, bj, Wr, br, d_ws);
    hipLaunchKernelGGL(nomc_main, dim3(B_), dim3(1024), 0, stream,
                       x_m, x_a, Wo, bo, Wfc, bfc, d_ws, out);
}

// Round 10
// 265.778 us; speedup vs baseline: 2.5787x; 1.0863x over previous
//
#include <hip/hip_runtime.h>

// NoMCOutModel round 10: r9 (plain-layout MFMA scan) + explicit LDS
// write->read ordering fences. r8/r9 failed with BIT-IDENTICAL absmax
// (10.1875) with/without swizzle -> common core bug. All MFMA layout facts
// are pinned by the passing produce phase (and both scan contractions are
// invariant to the A/B k-slot permutation), so the algebra is right; the
// only unpinned assumption is the same-wave cbuf ds_write -> ds_read
// handoff (r8/r9 deviated from r7's verified all-lane-write pattern and
// read via fresh b128 casts inside an unrolled loop). This round:
//  - cbuf written by ALL 64 lanes (lane l writes cbuf[l]), r7's pattern;
//  - asm volatile s_waitcnt lgkmcnt(0) + memory clobber between write and
//    A-frag reads (hard compiler+HW fence);
//  - loop-bottom compiler fence (no cross-iteration hoisting);
//  - same fence for the epilogue cfin handoff.

namespace {

constexpr int B_ = 256, T_ = 256, M_ = 8, AUX_ = 32, H_ = 64;
constexpr int NTILE = 288;               // (64*64 + 8*64)/16 logit col-tiles
constexpr float LOG2E = 1.4426950408889634f;

typedef __fp16 f16x2 __attribute__((ext_vector_type(2)));
typedef __fp16 f16x8 __attribute__((ext_vector_type(8)));
typedef float  f32x4 __attribute__((ext_vector_type(4)));
typedef int    i32x4 __attribute__((ext_vector_type(4)));

union V8 { f16x8 v; f16x2 p[4]; i32x4 i; };

#if __has_builtin(__builtin_amdgcn_exp2f)
#define EXP2(x) __builtin_amdgcn_exp2f(x)
#else
#define EXP2(x) exp2f(x)
#endif

template <int CTRL>
__device__ __forceinline__ float dpp_add(float v) {
    int t = __builtin_amdgcn_update_dpp(0, __builtin_bit_cast(int, v),
                                        CTRL, 0xf, 0xf, true);
    return v + __builtin_bit_cast(float, t);
}
__device__ __forceinline__ float sum16_all(float v) {
    v = dpp_add<0xB1>(v);   // quad_perm [1,0,3,2]
    v = dpp_add<0x4E>(v);   // quad_perm [2,3,0,1]
    v = dpp_add<0x141>(v);  // row_half_mirror
    v = dpp_add<0x140>(v);  // row_mirror
    return v;
}
__device__ __forceinline__ float sum64_uni(float v) {
    v = dpp_add<0x111>(v); v = dpp_add<0x112>(v); v = dpp_add<0x114>(v);
    v = dpp_add<0x118>(v); v = dpp_add<0x142>(v); v = dpp_add<0x143>(v);
    return __builtin_bit_cast(float,
        __builtin_amdgcn_readlane(__builtin_bit_cast(int, v), 63));
}

#define LDS_FENCE() __asm__ volatile("s_waitcnt lgkmcnt(0)" ::: "memory")
#define C_FENCE()   __asm__ volatile("" ::: "memory")

// ---------------- prep: W -> f16 MFMA B-frag layout in ws ----------------
// ws[gt*1024 + lane*16] : f16x8 frag, B[k = (lane>>4)*8 + j][n = gt*16+(lane&15)]
// ws + 288*1024 : float bias[4608] (log2e-scaled)
__global__ __launch_bounds__(64)
void nomc_prep(const float* __restrict__ Wj, const float* __restrict__ bj,
               const float* __restrict__ Wr, const float* __restrict__ br,
               void* __restrict__ ws)
{
    const int gt = blockIdx.x;           // 0..287
    const int l = threadIdx.x, q = l >> 4, l15 = l & 15;
    const float* src; const float* bsrc; int stride;
    if (gt < 256) { const int n = gt * 16 + l15;        src = Wr + n; bsrc = br + n; stride = 4096; }
    else          { const int n = (gt - 256) * 16 + l15; src = Wj + n; bsrc = bj + n; stride = 512; }
    V8 v;
#pragma unroll
    for (int j = 0; j < 4; ++j) {
        const float f0 = src[(q * 8 + 2 * j)     * stride] * LOG2E;
        const float f1 = src[(q * 8 + 2 * j + 1) * stride] * LOG2E;
        v.p[j] = __builtin_amdgcn_cvt_pkrtz(f0, f1);
    }
    *(i32x4*)((char*)ws + (size_t)gt * 1024 + l * 16) = v.i;
    if (l < 16)
        ((float*)((char*)ws + NTILE * 1024))[gt * 16 + l] = bsrc[0] * LOG2E;
}

// ---------------- main ----------------
__global__ __launch_bounds__(1024, 4)
void nomc_main(const float* __restrict__ x_m, const float* __restrict__ x_a,
               const float* __restrict__ Wo, const float* __restrict__ bo,
               const float* __restrict__ Wfc, const float* __restrict__ bfc,
               const void* __restrict__ ws, float* __restrict__ out)
{
    const int b = blockIdx.x, tid = threadIdx.x;
    const int w = tid >> 6, l = tid & 63, q = l >> 4, l15 = l & 15;

    __shared__ __align__(16) __fp16 RT[16][8][64][8];   // 131072 B  RT[t][h>>3][k][h&7]=e
    __shared__ __align__(16) __fp16 JT[16][64][8];      //  16384 B  JT[t][k][m]=e_j
    __shared__ float sinv[16][64];                      //   4096 B  1/rowsum(R)
    __shared__ __align__(16) __fp16 xj[16][32];         //   1024 B  [t][m]=xm/s, [8..31]=0
    __shared__ float xm_lds[T_][M_];                    //   8192 B
    __shared__ __align__(16) __fp16 cbuf[64];           //    128 B  c-hat staging (A-frag)
    __shared__ float cfin_lds[H_];                      //    256 B
    // total 161152 <= 163840

    {   // stage x_m; zero the xj pad (slots 8..31 must be 0 every launch)
        const float* xmb = x_m + (size_t)b * T_ * M_;
        for (int i = tid; i < T_ * M_; i += 1024) (&xm_lds[0][0])[i] = xmb[i];
        for (int i = tid; i < 16 * 32; i += 1024) (&xj[0][0])[i] = (__fp16)0.f;
    }
    __syncthreads();

    // wave w owns groups [g0, g0+ngrp); group = 4 tiles = one full softmax row.
    // waves 0..13 -> R rows (gg 0..63); waves 14,15 -> J rows (gg 64..71).
    const int ngrp = (w < 8) ? 5 : 4;
    const int g0   = (w < 8) ? w * 5 : 40 + (w - 8) * 4;
    const char* wsb = (const char*)ws;
    const float* wbias = (const float*)(wsb + NTILE * 1024);

    float c0 = 0.f, c1 = 0.f, c2 = 0.f, c3 = 0.f;   // c[kt*16 + l15]

    for (int it = 0; it < 16; ++it) {
        // ================= produce: 16 timesteps of exp(logits) =================
        V8 af;
        {   // A-frag: row = l15 -> t = it*16+l15; k = q*8+j
            const float* xa = x_a + ((size_t)b * T_ + it * 16 + l15) * AUX_ + q * 8;
            const f32x4 x0 = *(const f32x4*)xa;
            const f32x4 x1 = *(const f32x4*)(xa + 4);
            af.p[0] = __builtin_amdgcn_cvt_pkrtz(x0.x, x0.y);
            af.p[1] = __builtin_amdgcn_cvt_pkrtz(x0.z, x0.w);
            af.p[2] = __builtin_amdgcn_cvt_pkrtz(x1.x, x1.y);
            af.p[3] = __builtin_amdgcn_cvt_pkrtz(x1.z, x1.w);
        }

        for (int g = 0; g < ngrp; ++g) {
            const int gg = g0 + g;                       // 0..63 R row h; 64..71 J row m
            float es0 = 0.f, es1 = 0.f, es2 = 0.f, es3 = 0.f;
#pragma unroll
            for (int tt = 0; tt < 4; ++tt) {
                const int gt = gg * 4 + tt;
                V8 bf; bf.i = *(const i32x4*)(wsb + (size_t)gt * 1024 + l * 16);
                const float bv = wbias[gt * 16 + l15];
                f32x4 acc = {bv, bv, bv, bv};
                acc = __builtin_amdgcn_mfma_f32_16x16x32_f16(af.v, bf.v, acc, 0, 0, 0);
                const float e0 = EXP2(acc[0]), e1 = EXP2(acc[1]);
                const float e2 = EXP2(acc[2]), e3 = EXP2(acc[3]);
                const int kk = (tt << 4) + l15;
                if (gg < 64) {
                    const int hb = gg >> 3, p = gg & 7;  // plain layout
                    RT[q * 4 + 0][hb][kk][p] = (__fp16)e0;
                    RT[q * 4 + 1][hb][kk][p] = (__fp16)e1;
                    RT[q * 4 + 2][hb][kk][p] = (__fp16)e2;
                    RT[q * 4 + 3][hb][kk][p] = (__fp16)e3;
                } else {
                    const int mp = gg - 64;
                    JT[q * 4 + 0][kk][mp] = (__fp16)e0;
                    JT[q * 4 + 1][kk][mp] = (__fp16)e1;
                    JT[q * 4 + 2][kk][mp] = (__fp16)e2;
                    JT[q * 4 + 3][kk][mp] = (__fp16)e3;
                }
                es0 += e0; es1 += e1; es2 += e2; es3 += e3;
            }
            const float sr0 = sum16_all(es0), sr1 = sum16_all(es1);
            const float sr2 = sum16_all(es2), sr3 = sum16_all(es3);
            if (l15 == 0) {
                if (gg < 64) {
                    sinv[q * 4 + 0][gg] = __builtin_amdgcn_rcpf(sr0);
                    sinv[q * 4 + 1][gg] = __builtin_amdgcn_rcpf(sr1);
                    sinv[q * 4 + 2][gg] = __builtin_amdgcn_rcpf(sr2);
                    sinv[q * 4 + 3][gg] = __builtin_amdgcn_rcpf(sr3);
                } else {
                    const int m = gg - 64;
                    xj[q * 4 + 0][m] = (__fp16)(xm_lds[it * 16 + q * 4 + 0][m] * __builtin_amdgcn_rcpf(sr0));
                    xj[q * 4 + 1][m] = (__fp16)(xm_lds[it * 16 + q * 4 + 1][m] * __builtin_amdgcn_rcpf(sr1));
                    xj[q * 4 + 2][m] = (__fp16)(xm_lds[it * 16 + q * 4 + 2][m] * __builtin_amdgcn_rcpf(sr2));
                    xj[q * 4 + 3][m] = (__fp16)(xm_lds[it * 16 + q * 4 + 3][m] * __builtin_amdgcn_rcpf(sr3));
                }
            }
        }
        __syncthreads();

        // ================= scan: 16 serial MFMA matvecs (wave 15) =================
        if (w == 15) {
            for (int u = 0; u < 16; ++u) {
                // ALL lanes write their own cell (r7-verified handoff pattern)
                const float cown = (q == 0) ? c0 : (q == 1) ? c1 : (q == 2) ? c2 : c3;
                cbuf[l] = (__fp16)(cown * sinv[u][l]);
                LDS_FENCE();                             // write visible before reads
                V8 xjA; xjA.v = *(const f16x8*)&xj[u][q * 8];
                V8 A0;  A0.v  = *(const f16x8*)&cbuf[q * 8];
                V8 A1;  A1.v  = *(const f16x8*)&cbuf[32 + q * 8];
                float cn0, cn1, cn2, cn3;
#pragma unroll
                for (int kt = 0; kt < 4; ++kt) {
                    const int k = kt * 16 + l15;
                    V8 jB; jB.v = *(const f16x8*)&JT[u][k][0];
                    V8 b0; b0.v = *(const f16x8*)&RT[u][q][k][0];
                    V8 b1; b1.v = *(const f16x8*)&RT[u][4 + q][k][0];
                    f32x4 acc = {0.f, 0.f, 0.f, 0.f};
                    acc = __builtin_amdgcn_mfma_f32_16x16x32_f16(xjA.v, jB.v, acc, 0, 0, 0); // m_in
                    acc = __builtin_amdgcn_mfma_f32_16x16x32_f16(A0.v,  b0.v, acc, 0, 0, 0); // h 0..31
                    acc = __builtin_amdgcn_mfma_f32_16x16x32_f16(A1.v,  b1.v, acc, 0, 0, 0); // h 32..63
                    const float cv = acc[0];             // D rows all equal; col = l15
                    if (kt == 0) cn0 = cv; else if (kt == 1) cn1 = cv;
                    else if (kt == 2) cn2 = cv; else cn3 = cv;
                }
                c0 = cn0; c1 = cn1; c2 = cn2; c3 = cn3;
                C_FENCE();                               // no cross-iteration hoisting
            }
        }
        __syncthreads();
    }

    // ---- epilogue: out = (sigmoid(xa_T@Wo+bo) * c_T) @ Wfc + bfc ----
    if (w == 15) {
        const float cown = (q == 0) ? c0 : (q == 1) ? c1 : (q == 2) ? c2 : c3;
        cfin_lds[l] = cown;                              // all-lane write
        LDS_FENCE();
        const float* xa = x_a + ((size_t)b * T_ + (T_ - 1)) * AUX_;
        float L = bo[l];
#pragma unroll
        for (int a = 0; a < AUX_; ++a) L = fmaf(xa[a], Wo[a * H_ + l], L);
        const float o = 1.0f / (1.0f + __expf(-L));
        const float cfin = cfin_lds[l];
        float p = (o * cfin) * Wfc[l];
        p = sum64_uni(p);
        if (l == 0) out[b] = p + bfc[0];
        out[B_ + b * H_ + l] = cfin;                     // c_final, coalesced
    }
}

} // namespace

extern "C" void kernel_launch(void* const* d_in, const int* in_sizes, int n_in,
                              void* d_out, int out_size, void* d_ws, size_t ws_size,
                              hipStream_t stream) {
    const float* x_m = (const float*)d_in[0];
    const float* x_a = (const float*)d_in[1];
    const float* Wj  = (const float*)d_in[2];
    const float* bj  = (const float*)d_in[3];
    const float* Wr  = (const float*)d_in[4];
    const float* br  = (const float*)d_in[5];
    const float* Wo  = (const float*)d_in[6];
    const float* bo  = (const float*)d_in[7];
    const float* Wfc = (const float*)d_in[8];
    const float* bfc = (const float*)d_in[9];
    float* out = (float*)d_out;

    hipLaunchKernelGGL(nomc_prep, dim3(NTILE), dim3(64), 0, stream,
                       Wj, bj, Wr, br, d_ws);
    hipLaunchKernelGGL(nomc_main, dim3(B_), dim3(1024), 0, stream,
                       x_m, x_a, Wo, bo, Wfc, bfc, d_ws, out);
}